// Round 1
// baseline (647.546 us; speedup 1.0000x reference)
//
#include <hip/hip_runtime.h>
#include <hip/hip_fp16.h>
#include <math.h>

// ---------------------------------------------------------------------------
// FeedForward: LN -> act-int8-fakequant x ternary-weight qlinear -> GELU(erf)
//              -> qlinear.  Exact-integer i8 MFMA GEMMs; exact quantile via
//              radix-select on float bit patterns.
// Shapes: x[16384,1024], w1[4096,1024], w2[1024,4096], out[16384,1024] fp32.
// ---------------------------------------------------------------------------

#define M_ROWS 16384
#define D_DIM  1024
#define H_DIM  4096

typedef int i32x4 __attribute__((ext_vector_type(4)));

struct QState {
  unsigned bin_k, bin_k1;                 // level-1 (top-12-bit) bins of a[k], a[k+1]
  unsigned long long below_k, below_k1;   // count of elements strictly below each bin
  float amax, scale;                      // final robust absmax and s = 127/amax
};

#define AS1 __attribute__((address_space(1)))
#define AS3 __attribute__((address_space(3)))

__device__ __forceinline__ void load_lds16(const void* g, void* l) {
  __builtin_amdgcn_global_load_lds((const AS1 void*)g, (AS3 void*)l, 16, 0, 0);
}

// ---------------------------------------------------------------------------
// LayerNorm: one block (256 thr) per row of 1024.
// ---------------------------------------------------------------------------
__device__ __forceinline__ float block_sum256(float v, float* lds) {
#pragma unroll
  for (int o = 32; o > 0; o >>= 1) v += __shfl_down(v, o, 64);
  int t = threadIdx.x;
  __syncthreads();
  if ((t & 63) == 0) lds[t >> 6] = v;
  __syncthreads();
  return lds[0] + lds[1] + lds[2] + lds[3];
}

__global__ __launch_bounds__(256) void k_layernorm(
    const float* __restrict__ x, const float* __restrict__ g,
    const float* __restrict__ b, float* __restrict__ out) {
  __shared__ float lds[4];
  int row = blockIdx.x, t = threadIdx.x;
  float4 v = ((const float4*)(x + (size_t)row * D_DIM))[t];
  float s = v.x + v.y + v.z + v.w;
  s = block_sum256(s, lds);
  float mu = s * (1.0f / D_DIM);
  float d0 = v.x - mu, d1 = v.y - mu, d2 = v.z - mu, d3 = v.w - mu;
  float ss = d0 * d0 + d1 * d1 + d2 * d2 + d3 * d3;
  ss = block_sum256(ss, lds);
  float inv = 1.0f / sqrtf(ss * (1.0f / D_DIM) + 1e-5f);
  float4 gg = ((const float4*)g)[t];
  float4 bb = ((const float4*)b)[t];
  float4 o;
  o.x = d0 * inv * gg.x + bb.x;
  o.y = d1 * inv * gg.y + bb.y;
  o.z = d2 * inv * gg.z + bb.z;
  o.w = d3 * inv * gg.w + bb.w;
  ((float4*)(out + (size_t)row * D_DIM))[t] = o;
}

// ---------------------------------------------------------------------------
// Weight ternary quantization: gamma = mean|w| + 1e-5; q = clip(rint(w/g),-1,1)
// ---------------------------------------------------------------------------
__global__ __launch_bounds__(256) void k_absmean(const float4* __restrict__ p,
                                                 size_t n4, double* __restrict__ out) {
  double s = 0.0;
  size_t stride = (size_t)gridDim.x * blockDim.x;
  for (size_t i = (size_t)blockIdx.x * blockDim.x + threadIdx.x; i < n4; i += stride) {
    float4 v = p[i];
    s += (double)fabsf(v.x) + (double)fabsf(v.y) + (double)fabsf(v.z) + (double)fabsf(v.w);
  }
#pragma unroll
  for (int o = 32; o > 0; o >>= 1) s += __shfl_down(s, o, 64);
  __shared__ double ds[4];
  int t = threadIdx.x;
  if ((t & 63) == 0) ds[t >> 6] = s;
  __syncthreads();
  if (t == 0) atomicAdd(out, ds[0] + ds[1] + ds[2] + ds[3]);
}

__device__ __forceinline__ int tern1(float w, float gamma) {
  return (int)fminf(1.f, fmaxf(-1.f, rintf(w / gamma)));
}

__global__ __launch_bounds__(256) void k_wquant(const float4* __restrict__ w,
                                                unsigned* __restrict__ wq, size_t n4,
                                                const double* __restrict__ sump,
                                                double inv_n, float* __restrict__ gamma_out) {
  float gamma = (float)(*sump * inv_n) + 1e-5f;
  if (blockIdx.x == 0 && threadIdx.x == 0) *gamma_out = gamma;
  size_t stride = (size_t)gridDim.x * blockDim.x;
  for (size_t i = (size_t)blockIdx.x * blockDim.x + threadIdx.x; i < n4; i += stride) {
    float4 v = w[i];
    int a = tern1(v.x, gamma), b = tern1(v.y, gamma), c = tern1(v.z, gamma), d = tern1(v.w, gamma);
    wq[i] = (unsigned)(a & 255) | ((unsigned)(b & 255) << 8) |
            ((unsigned)(c & 255) << 16) | ((unsigned)(d & 255) << 24);
  }
}

// ---------------------------------------------------------------------------
// Exact quantile machinery (radix select on |x| float bits; monotone for >=0)
// ---------------------------------------------------------------------------
__global__ __launch_bounds__(256) void k_hist1_f32(const float4* __restrict__ p, size_t n4,
                                                   unsigned* __restrict__ hist) {
  __shared__ unsigned h[4][2048];
  int t = threadIdx.x, wv = t >> 6;
  for (int i = t; i < 8192; i += 256) ((unsigned*)h)[i] = 0;
  __syncthreads();
  size_t stride = (size_t)gridDim.x * blockDim.x;
  for (size_t i = (size_t)blockIdx.x * blockDim.x + t; i < n4; i += stride) {
    float4 v = p[i];
    atomicAdd(&h[wv][__float_as_uint(fabsf(v.x)) >> 20], 1u);
    atomicAdd(&h[wv][__float_as_uint(fabsf(v.y)) >> 20], 1u);
    atomicAdd(&h[wv][__float_as_uint(fabsf(v.z)) >> 20], 1u);
    atomicAdd(&h[wv][__float_as_uint(fabsf(v.w)) >> 20], 1u);
  }
  __syncthreads();
  for (int i = t; i < 2048; i += 256) {
    unsigned s = h[0][i] + h[1][i] + h[2][i] + h[3][i];
    if (s) atomicAdd(&hist[i], s);
  }
}

__device__ __forceinline__ void unpack8(uint4 u, float* f) {
  __half2 h;
  h = *(__half2*)&u.x; f[0] = __low2float(h); f[1] = __high2float(h);
  h = *(__half2*)&u.y; f[2] = __low2float(h); f[3] = __high2float(h);
  h = *(__half2*)&u.z; f[4] = __low2float(h); f[5] = __high2float(h);
  h = *(__half2*)&u.w; f[6] = __low2float(h); f[7] = __high2float(h);
}

__global__ __launch_bounds__(256) void k_hist1_f16(const uint4* __restrict__ p, size_t n8,
                                                   unsigned* __restrict__ hist) {
  __shared__ unsigned h[4][2048];
  int t = threadIdx.x, wv = t >> 6;
  for (int i = t; i < 8192; i += 256) ((unsigned*)h)[i] = 0;
  __syncthreads();
  size_t stride = (size_t)gridDim.x * blockDim.x;
  for (size_t i = (size_t)blockIdx.x * blockDim.x + t; i < n8; i += stride) {
    float f[8];
    unpack8(p[i], f);
#pragma unroll
    for (int j = 0; j < 8; ++j) atomicAdd(&h[wv][__float_as_uint(fabsf(f[j])) >> 20], 1u);
  }
  __syncthreads();
  for (int i = t; i < 2048; i += 256) {
    unsigned s = h[0][i] + h[1][i] + h[2][i] + h[3][i];
    if (s) atomicAdd(&hist[i], s);
  }
}

// scan level-1 histogram; locate bins containing ranks k and k+1 (0-indexed)
__global__ __launch_bounds__(256) void k_scan1(const unsigned* __restrict__ hist,
                                               QState* __restrict__ qs, unsigned long long k) {
  __shared__ unsigned tsum[256];
  __shared__ unsigned long long pre[256];
  int t = threadIdx.x;
  unsigned v[8]; unsigned s = 0;
#pragma unroll
  for (int j = 0; j < 8; ++j) { v[j] = hist[t * 8 + j]; s += v[j]; }
  tsum[t] = s;
  __syncthreads();
  if (t == 0) {
    unsigned long long c = 0;
    for (int i = 0; i < 256; ++i) { pre[i] = c; c += tsum[i]; }
  }
  __syncthreads();
  unsigned long long base = pre[t];
#pragma unroll
  for (int j = 0; j < 8; ++j) {
    if (base <= k && k < base + v[j]) { qs->bin_k = t * 8 + j; qs->below_k = base; }
    if (base <= k + 1 && k + 1 < base + v[j]) { qs->bin_k1 = t * 8 + j; qs->below_k1 = base; }
    base += v[j];
  }
}

// level-2: low-20-bit histogram restricted to the selected level-1 bin(s)
__global__ __launch_bounds__(256) void k_hist2_f32(const float4* __restrict__ p, size_t n4,
                                                   const QState* __restrict__ qs,
                                                   unsigned* __restrict__ hist2) {
  unsigned b0 = qs->bin_k, b1 = qs->bin_k1;
  size_t stride = (size_t)gridDim.x * blockDim.x;
  for (size_t i = (size_t)blockIdx.x * blockDim.x + threadIdx.x; i < n4; i += stride) {
    float4 v = p[i];
    float f[4] = {v.x, v.y, v.z, v.w};
#pragma unroll
    for (int j = 0; j < 4; ++j) {
      unsigned u = __float_as_uint(fabsf(f[j]));
      unsigned hb = u >> 20;
      if (hb == b0) atomicAdd(&hist2[u & 0xFFFFFu], 1u);
      else if (hb == b1) atomicAdd(&hist2[(1u << 20) + (u & 0xFFFFFu)], 1u);
    }
  }
}

__global__ __launch_bounds__(256) void k_hist2_f16(const uint4* __restrict__ p, size_t n8,
                                                   const QState* __restrict__ qs,
                                                   unsigned* __restrict__ hist2) {
  unsigned b0 = qs->bin_k, b1 = qs->bin_k1;
  size_t stride = (size_t)gridDim.x * blockDim.x;
  for (size_t i = (size_t)blockIdx.x * blockDim.x + threadIdx.x; i < n8; i += stride) {
    float f[8];
    unpack8(p[i], f);
#pragma unroll
    for (int j = 0; j < 8; ++j) {
      unsigned u = __float_as_uint(fabsf(f[j]));
      unsigned hb = u >> 20;
      if (hb == b0) atomicAdd(&hist2[u & 0xFFFFFu], 1u);
      else if (hb == b1) atomicAdd(&hist2[(1u << 20) + (u & 0xFFFFFu)], 1u);
    }
  }
}

// partial sums of the 2x(1M) level-2 histograms in 1024-bin chunks
__global__ __launch_bounds__(256) void k_scan2a(const unsigned* __restrict__ hist2,
                                                unsigned* __restrict__ parts) {
  int b = blockIdx.x;  // 0..2047
  const unsigned* src = hist2 + (size_t)b * 1024;
  int t = threadIdx.x;
  unsigned s = src[t * 4] + src[t * 4 + 1] + src[t * 4 + 2] + src[t * 4 + 3];
#pragma unroll
  for (int o = 32; o > 0; o >>= 1) s += __shfl_down(s, o, 64);
  __shared__ unsigned w4[4];
  if ((t & 63) == 0) w4[t >> 6] = s;
  __syncthreads();
  if (t == 0) parts[b] = w4[0] + w4[1] + w4[2] + w4[3];
}

// block-cooperative: find index in 1024-array where cumulative crosses rank r
__device__ void find1024(const unsigned* __restrict__ arr, unsigned long long r,
                         unsigned* idx_out, unsigned long long* rem_out) {
  __shared__ unsigned fsum[256];
  __shared__ unsigned long long fpre[256];
  __shared__ unsigned fidx;
  __shared__ unsigned long long frem;
  int t = threadIdx.x;
  __syncthreads();
  unsigned v[4]; unsigned s = 0;
#pragma unroll
  for (int j = 0; j < 4; ++j) { v[j] = arr[t * 4 + j]; s += v[j]; }
  fsum[t] = s;
  __syncthreads();
  if (t == 0) {
    unsigned long long c = 0;
    for (int i = 0; i < 256; ++i) { fpre[i] = c; c += fsum[i]; }
  }
  __syncthreads();
  unsigned long long base = fpre[t];
#pragma unroll
  for (int j = 0; j < 4; ++j) {
    if (base <= r && r < base + v[j]) { fidx = t * 4 + j; frem = r - base; }
    base += v[j];
  }
  __syncthreads();
  *idx_out = fidx;
  *rem_out = frem;
}

__global__ __launch_bounds__(256) void k_scan2b(const unsigned* __restrict__ hist2,
                                                const unsigned* __restrict__ parts,
                                                QState* __restrict__ qs,
                                                unsigned long long k, double frac) {
  unsigned c0, j0; unsigned long long rem, d;
  // value at rank k (always in hist2 region 0)
  find1024(parts, k - qs->below_k, &c0, &rem);
  find1024(hist2 + (size_t)c0 * 1024, rem, &j0, &d);
  unsigned val_k = (qs->bin_k << 20) | (c0 * 1024 + j0);
  // value at rank k+1
  unsigned sel, bh; unsigned long long r1;
  if (qs->bin_k1 == qs->bin_k) { sel = 0; r1 = k + 1 - qs->below_k; bh = qs->bin_k; }
  else { sel = 1; r1 = k + 1 - qs->below_k1; bh = qs->bin_k1; }
  unsigned c1, j1;
  find1024(parts + sel * 1024, r1, &c1, &rem);
  find1024(hist2 + (size_t)sel * (1u << 20) + (size_t)c1 * 1024, rem, &j1, &d);
  unsigned val_k1 = (bh << 20) | (c1 * 1024 + j1);
  if (threadIdx.x == 0) {
    double a = (double)__uint_as_float(val_k);
    double b = (double)__uint_as_float(val_k1);
    // numpy lerp form (symmetric around 0.5)
    double qv = (frac >= 0.5) ? (b - (b - a) * (1.0 - frac)) : (a + (b - a) * frac);
    float amax = fmaxf((float)qv, 1e-5f);
    qs->amax = amax;
    qs->scale = 127.0f / amax;
  }
}

// ---------------------------------------------------------------------------
// Activation quantization to int8
// ---------------------------------------------------------------------------
__device__ __forceinline__ unsigned qpack4(float a, float b, float c, float d, float s) {
  int qa = (int)fminf(127.f, fmaxf(-128.f, rintf(a * s)));
  int qb = (int)fminf(127.f, fmaxf(-128.f, rintf(b * s)));
  int qc = (int)fminf(127.f, fmaxf(-128.f, rintf(c * s)));
  int qd = (int)fminf(127.f, fmaxf(-128.f, rintf(d * s)));
  return (unsigned)(qa & 255) | ((unsigned)(qb & 255) << 8) |
         ((unsigned)(qc & 255) << 16) | ((unsigned)(qd & 255) << 24);
}

__global__ __launch_bounds__(256) void k_quant_f32(const float4* __restrict__ p,
                                                   unsigned* __restrict__ q, size_t n4,
                                                   const QState* __restrict__ qs) {
  float s = qs->scale;
  size_t stride = (size_t)gridDim.x * blockDim.x;
  for (size_t i = (size_t)blockIdx.x * blockDim.x + threadIdx.x; i < n4; i += stride) {
    float4 v = p[i];
    q[i] = qpack4(v.x, v.y, v.z, v.w, s);
  }
}

__global__ __launch_bounds__(256) void k_quant_f16(const uint4* __restrict__ p,
                                                   uint2* __restrict__ q, size_t n8,
                                                   const QState* __restrict__ qs) {
  float s = qs->scale;
  size_t stride = (size_t)gridDim.x * blockDim.x;
  for (size_t i = (size_t)blockIdx.x * blockDim.x + threadIdx.x; i < n8; i += stride) {
    float f[8];
    unpack8(p[i], f);
    uint2 r;
    r.x = qpack4(f[0], f[1], f[2], f[3], s);
    r.y = qpack4(f[4], f[5], f[6], f[7], s);
    q[i] = r;
  }
}

// ---------------------------------------------------------------------------
// int8 GEMM, C = A[M,K] * B[N,K]^T, m97 structure: 128x128 tile, BK=64,
// global_load_lds width-16 staging with XOR granule swizzle, 4 waves,
// each wave 4x4 of 16x16x64 i8 MFMAs. Epilogue: dequant (+GELU->fp16 | fp32).
// ---------------------------------------------------------------------------
template <bool GELU>
__global__ __launch_bounds__(256) void k_gemm(const signed char* __restrict__ A,
                                              const signed char* __restrict__ B,
                                              int K, int N, void* __restrict__ outp,
                                              const float* __restrict__ gamma_p,
                                              const QState* __restrict__ qs) {
  __shared__ __align__(16) signed char As[8192];
  __shared__ __align__(16) signed char Bs[8192];
  const int t = threadIdx.x;
  const int l = t & 63;
  const int wv = t >> 6;
  const int wr = (wv >> 1) * 64, wc = (wv & 1) * 64;
  const int m0 = blockIdx.y * 128, n0 = blockIdx.x * 128;

  // staging: slot g holds global granule (row g>>2, col (g&3)^((g>>3)&3))
  const signed char* ag[2]; const signed char* bg[2];
  signed char* al[2]; signed char* bl[2];
#pragma unroll
  for (int c = 0; c < 2; ++c) {
    int g = c * 256 + t;
    int r = g >> 2;
    int cg = (g & 3) ^ ((g >> 3) & 3);
    ag[c] = A + (size_t)(m0 + r) * K + cg * 16;
    bg[c] = B + (size_t)(n0 + r) * K + cg * 16;
    al[c] = As + g * 16;
    bl[c] = Bs + g * 16;
  }

  // fragment LDS byte offsets (row m, k-granule c' = l>>4, swizzle (m>>1)&3)
  int a_off[4], b_off[4];
#pragma unroll
  for (int i = 0; i < 4; ++i) {
    int am = wr + i * 16 + (l & 15);
    a_off[i] = (am * 4 + ((l >> 4) ^ ((am >> 1) & 3))) * 16;
    int bn = wc + i * 16 + (l & 15);
    b_off[i] = (bn * 4 + ((l >> 4) ^ ((bn >> 1) & 3))) * 16;
  }

  i32x4 acc[4][4];
#pragma unroll
  for (int mi = 0; mi < 4; ++mi)
#pragma unroll
    for (int ni = 0; ni < 4; ++ni) {
      i32x4 z = {0, 0, 0, 0};
      acc[mi][ni] = z;
    }

  for (int kk = 0; kk < K; kk += 64) {
    __syncthreads();
#pragma unroll
    for (int c = 0; c < 2; ++c) {
      load_lds16(ag[c] + kk, al[c]);
      load_lds16(bg[c] + kk, bl[c]);
    }
    __syncthreads();
    i32x4 af[4], bf[4];
#pragma unroll
    for (int i = 0; i < 4; ++i) af[i] = *(const i32x4*)(As + a_off[i]);
#pragma unroll
    for (int i = 0; i < 4; ++i) bf[i] = *(const i32x4*)(Bs + b_off[i]);
#pragma unroll
    for (int mi = 0; mi < 4; ++mi)
#pragma unroll
      for (int ni = 0; ni < 4; ++ni)
        acc[mi][ni] = __builtin_amdgcn_mfma_i32_16x16x64_i8(af[mi], bf[ni], acc[mi][ni], 0, 0, 0);
  }

  // dequant scale: xq = n/s, wq = m*gamma -> contribution (gamma/s) * (n·m)
  const float cs = (*gamma_p) / qs->scale;
  const int col0 = n0 + wc + (l & 15);
  const int row00 = m0 + wr + (l >> 4) * 4;
#pragma unroll
  for (int mi = 0; mi < 4; ++mi) {
#pragma unroll
    for (int ni = 0; ni < 4; ++ni) {
      int col = col0 + ni * 16;
      int rbase = row00 + mi * 16;
#pragma unroll
      for (int r = 0; r < 4; ++r) {
        float v = cs * (float)acc[mi][ni][r];
        size_t idx = (size_t)(rbase + r) * N + col;
        if (GELU) {
          float gl = 0.5f * v * (1.0f + erff(v * 0.70710678118654752f));
          ((__half*)outp)[idx] = __float2half(gl);
        } else {
          ((float*)outp)[idx] = v;
        }
      }
    }
  }
}

// ---------------------------------------------------------------------------
// Launcher.  Workspace layout (bytes):
//   [0,128M):  h1 fp32 (64M), later reused as h2 fp16 (128M)
//   [128M):    xq1 int8 16M      [144M): xq2 int8 64M
//   [208M):    w1q 4M            [212M): w2q 4M
//   [216M):    hist2 q1 [2][1M] u32 (8M)   [224M): hist2 q2 (8M)
//   [232M):    small: hist1a(8K) hist1b(8K) parts q1(8K) parts q2(8K)
//              wsum[2] dbl, gamma[2] f32, QState[2]
// ---------------------------------------------------------------------------
extern "C" void kernel_launch(void* const* d_in, const int* in_sizes, int n_in,
                              void* d_out, int out_size, void* d_ws, size_t ws_size,
                              hipStream_t stream) {
  const float* x = (const float*)d_in[0];
  const float* ln_g = (const float*)d_in[1];
  const float* ln_b = (const float*)d_in[2];
  const float* w1 = (const float*)d_in[3];
  const float* w2 = (const float*)d_in[4];
  float* out = (float*)d_out;

  char* ws = (char*)d_ws;
  float* h1 = (float*)ws;
  __half* h2 = (__half*)ws;
  signed char* xq1 = (signed char*)(ws + ((size_t)128 << 20));
  signed char* xq2 = (signed char*)(ws + ((size_t)144 << 20));
  signed char* w1q = (signed char*)(ws + ((size_t)208 << 20));
  signed char* w2q = (signed char*)(ws + ((size_t)212 << 20));
  unsigned* hist2q1 = (unsigned*)(ws + ((size_t)216 << 20));
  unsigned* hist2q2 = (unsigned*)(ws + ((size_t)224 << 20));
  char* sm = ws + ((size_t)232 << 20);
  unsigned* hist1a = (unsigned*)sm;
  unsigned* hist1b = (unsigned*)(sm + 8192);
  unsigned* partsq1 = (unsigned*)(sm + 16384);
  unsigned* partsq2 = (unsigned*)(sm + 24576);
  double* wsum = (double*)(sm + 32768);
  float* gamma = (float*)(sm + 32768 + 16);
  QState* qs = (QState*)(sm + 32768 + 32);

  // zero hist2 regions + small region (ws is poisoned 0xAA before every call)
  hipMemsetAsync(ws + ((size_t)216 << 20), 0, ((size_t)16 << 20) + 65536, stream);

  // quantile ranks (match np: virtual index = (1-0.005)*(N-1) in fp64)
  const double qq = 1.0 - 0.005;
  const unsigned long long N1 = (unsigned long long)M_ROWS * D_DIM;   // 16777216
  const unsigned long long N2 = (unsigned long long)M_ROWS * H_DIM;   // 67108864
  double idx1 = qq * (double)(N1 - 1);
  double idx2 = qq * (double)(N2 - 1);
  unsigned long long k1 = (unsigned long long)idx1;
  unsigned long long k2 = (unsigned long long)idx2;
  double frac1 = idx1 - (double)k1;
  double frac2 = idx2 - (double)k2;

  const size_t nW4 = (size_t)H_DIM * D_DIM / 4;  // 1048576 quads (both weights)
  const double inv_nW = 1.0 / (double)(H_DIM * D_DIM);

  // ---- weights ----
  k_absmean<<<512, 256, 0, stream>>>((const float4*)w1, nW4, wsum + 0);
  k_absmean<<<512, 256, 0, stream>>>((const float4*)w2, nW4, wsum + 1);
  k_wquant<<<1024, 256, 0, stream>>>((const float4*)w1, (unsigned*)w1q, nW4, wsum + 0, inv_nW, gamma + 0);
  k_wquant<<<1024, 256, 0, stream>>>((const float4*)w2, (unsigned*)w2q, nW4, wsum + 1, inv_nW, gamma + 1);

  // ---- layernorm ----
  k_layernorm<<<M_ROWS, 256, 0, stream>>>(x, ln_g, ln_b, h1);

  // ---- quantile 1 (|h1|, N1 elems) ----
  const size_t n4_1 = N1 / 4;
  k_hist1_f32<<<1024, 256, 0, stream>>>((const float4*)h1, n4_1, hist1a);
  k_scan1<<<1, 256, 0, stream>>>(hist1a, qs + 0, k1);
  k_hist2_f32<<<1024, 256, 0, stream>>>((const float4*)h1, n4_1, qs + 0, hist2q1);
  k_scan2a<<<2048, 256, 0, stream>>>(hist2q1, partsq1);
  k_scan2b<<<1, 256, 0, stream>>>(hist2q1, partsq1, qs + 0, k1, frac1);
  k_quant_f32<<<1024, 256, 0, stream>>>((const float4*)h1, (unsigned*)xq1, n4_1, qs + 0);

  // ---- GEMM1: [16384,1024] x [4096,1024]^T -> gelu -> h2 fp16 ----
  k_gemm<true><<<dim3(H_DIM / 128, M_ROWS / 128), 256, 0, stream>>>(
      xq1, w1q, D_DIM, H_DIM, (void*)h2, gamma + 0, qs + 0);

  // ---- quantile 2 (|h2|, N2 elems, fp16) ----
  const size_t n8_2 = N2 / 8;
  k_hist1_f16<<<2048, 256, 0, stream>>>((const uint4*)h2, n8_2, hist1b);
  k_scan1<<<1, 256, 0, stream>>>(hist1b, qs + 1, k2);
  k_hist2_f16<<<2048, 256, 0, stream>>>((const uint4*)h2, n8_2, qs + 1, hist2q2);
  k_scan2a<<<2048, 256, 0, stream>>>(hist2q2, partsq2);
  k_scan2b<<<1, 256, 0, stream>>>(hist2q2, partsq2, qs + 1, k2, frac2);
  k_quant_f16<<<2048, 256, 0, stream>>>((const uint4*)h2, (uint2*)xq2, n8_2, qs + 1);

  // ---- GEMM2: [16384,4096] x [1024,4096]^T -> out fp32 ----
  k_gemm<false><<<dim3(D_DIM / 128, M_ROWS / 128), 256, 0, stream>>>(
      xq2, w2q, H_DIM, D_DIM, (void*)out, gamma + 1, qs + 1);
}

// Round 2
// 507.769 us; speedup vs baseline: 1.2753x; 1.2753x over previous
//
#include <hip/hip_runtime.h>
#include <hip/hip_fp16.h>
#include <math.h>

// ---------------------------------------------------------------------------
// FeedForward: LN -> act-int8-fakequant x ternary-weight qlinear -> GELU(erf)
//              -> qlinear.  Exact-integer i8 MFMA GEMMs.
// h1 and h2 both fp16 -> exact per-tensor quantile via single 32768-bin
// histogram over the fp16 |bits| (monotone).  GELU via A&S 7.1.26 erf.
// Shapes: x[16384,1024], w1[4096,1024], w2[1024,4096], out[16384,1024] fp32.
// ---------------------------------------------------------------------------

#define M_ROWS 16384
#define D_DIM  1024
#define H_DIM  4096

typedef int i32x4 __attribute__((ext_vector_type(4)));

#define AS1 __attribute__((address_space(1)))
#define AS3 __attribute__((address_space(3)))

__device__ __forceinline__ void load_lds16(const void* g, void* l) {
  __builtin_amdgcn_global_load_lds((const AS1 void*)g, (AS3 void*)l, 16, 0, 0);
}

// ---------------------------------------------------------------------------
// LayerNorm: one block (256 thr) per row of 1024; fp16 output.
// ---------------------------------------------------------------------------
__device__ __forceinline__ float block_sum256(float v, float* lds) {
#pragma unroll
  for (int o = 32; o > 0; o >>= 1) v += __shfl_down(v, o, 64);
  int t = threadIdx.x;
  __syncthreads();
  if ((t & 63) == 0) lds[t >> 6] = v;
  __syncthreads();
  return lds[0] + lds[1] + lds[2] + lds[3];
}

__global__ __launch_bounds__(256) void k_layernorm(
    const float* __restrict__ x, const float* __restrict__ g,
    const float* __restrict__ b, __half* __restrict__ out) {
  __shared__ float lds[4];
  int row = blockIdx.x, t = threadIdx.x;
  float4 v = ((const float4*)(x + (size_t)row * D_DIM))[t];
  float s = v.x + v.y + v.z + v.w;
  s = block_sum256(s, lds);
  float mu = s * (1.0f / D_DIM);
  float d0 = v.x - mu, d1 = v.y - mu, d2 = v.z - mu, d3 = v.w - mu;
  float ss = d0 * d0 + d1 * d1 + d2 * d2 + d3 * d3;
  ss = block_sum256(ss, lds);
  float inv = 1.0f / sqrtf(ss * (1.0f / D_DIM) + 1e-5f);
  float4 gg = ((const float4*)g)[t];
  float4 bb = ((const float4*)b)[t];
  __half2 p0 = __floats2half2_rn(d0 * inv * gg.x + bb.x, d1 * inv * gg.y + bb.y);
  __half2 p1 = __floats2half2_rn(d2 * inv * gg.z + bb.z, d3 * inv * gg.w + bb.w);
  uint2 st;
  st.x = *(unsigned*)&p0;
  st.y = *(unsigned*)&p1;
  ((uint2*)(out + (size_t)row * D_DIM))[t] = st;
}

// ---------------------------------------------------------------------------
// Weight ternary quantization: gamma = mean|w| + 1e-5; q = clip(rint(w/g),-1,1)
// ---------------------------------------------------------------------------
__global__ __launch_bounds__(256) void k_absmean(const float4* __restrict__ p,
                                                 size_t n4, double* __restrict__ out) {
  double s = 0.0;
  size_t stride = (size_t)gridDim.x * blockDim.x;
  for (size_t i = (size_t)blockIdx.x * blockDim.x + threadIdx.x; i < n4; i += stride) {
    float4 v = p[i];
    s += (double)fabsf(v.x) + (double)fabsf(v.y) + (double)fabsf(v.z) + (double)fabsf(v.w);
  }
#pragma unroll
  for (int o = 32; o > 0; o >>= 1) s += __shfl_down(s, o, 64);
  __shared__ double ds[4];
  int t = threadIdx.x;
  if ((t & 63) == 0) ds[t >> 6] = s;
  __syncthreads();
  if (t == 0) atomicAdd(out, ds[0] + ds[1] + ds[2] + ds[3]);
}

__device__ __forceinline__ int tern1(float w, float gamma) {
  return (int)fminf(1.f, fmaxf(-1.f, rintf(w / gamma)));
}

__global__ __launch_bounds__(256) void k_wquant(const float4* __restrict__ w,
                                                unsigned* __restrict__ wq, size_t n4,
                                                const double* __restrict__ sump,
                                                double inv_n, float* __restrict__ gamma_out) {
  float gamma = (float)(*sump * inv_n) + 1e-5f;
  if (blockIdx.x == 0 && threadIdx.x == 0) *gamma_out = gamma;
  size_t stride = (size_t)gridDim.x * blockDim.x;
  for (size_t i = (size_t)blockIdx.x * blockDim.x + threadIdx.x; i < n4; i += stride) {
    float4 v = w[i];
    int a = tern1(v.x, gamma), b = tern1(v.y, gamma), c = tern1(v.z, gamma), d = tern1(v.w, gamma);
    wq[i] = (unsigned)(a & 255) | ((unsigned)(b & 255) << 8) |
            ((unsigned)(c & 255) << 16) | ((unsigned)(d & 255) << 24);
  }
}

// ---------------------------------------------------------------------------
// Exact fp16 quantile: 32768-bin histogram over |bits| (monotone for halfs).
// One 128 KB LDS copy per block (1 block/CU); sparse merge to global.
// ---------------------------------------------------------------------------
__global__ __launch_bounds__(512) void k_hist16(const uint4* __restrict__ p, size_t n8,
                                                unsigned* __restrict__ hist) {
  extern __shared__ unsigned h[];  // 32768 bins
  int t = threadIdx.x;
  for (int i = t; i < 32768; i += 512) h[i] = 0;
  __syncthreads();
  size_t stride = (size_t)gridDim.x * 512;
  for (size_t i = (size_t)blockIdx.x * 512 + t; i < n8; i += stride) {
    uint4 u = p[i];
    atomicAdd(&h[u.x & 0x7FFFu], 1u);
    atomicAdd(&h[(u.x >> 16) & 0x7FFFu], 1u);
    atomicAdd(&h[u.y & 0x7FFFu], 1u);
    atomicAdd(&h[(u.y >> 16) & 0x7FFFu], 1u);
    atomicAdd(&h[u.z & 0x7FFFu], 1u);
    atomicAdd(&h[(u.z >> 16) & 0x7FFFu], 1u);
    atomicAdd(&h[u.w & 0x7FFFu], 1u);
    atomicAdd(&h[(u.w >> 16) & 0x7FFFu], 1u);
  }
  __syncthreads();
  for (int i = t; i < 32768; i += 512) {
    unsigned c = h[i];
    if (c) atomicAdd(&hist[i], c);
  }
}

// scan 32768 bins; order stats a[k], a[k+1]; numpy lerp -> amax, scale
__global__ __launch_bounds__(256) void k_scanq(const unsigned* __restrict__ hist,
                                               float* __restrict__ scl,
                                               unsigned long long k, double frac) {
  __shared__ unsigned tsum[256];
  __shared__ unsigned long long pre[256];
  __shared__ unsigned vk, vk1;
  int t = threadIdx.x;
  unsigned s = 0;
  for (int j = 0; j < 128; ++j) s += hist[t * 128 + j];
  tsum[t] = s;
  __syncthreads();
  if (t == 0) {
    unsigned long long c = 0;
    for (int i = 0; i < 256; ++i) { pre[i] = c; c += tsum[i]; }
  }
  __syncthreads();
  unsigned long long base = pre[t];
  for (int j = 0; j < 128; ++j) {
    unsigned c = hist[t * 128 + j];
    if (base <= k && k < base + c) vk = t * 128 + j;
    if (base <= k + 1 && k + 1 < base + c) vk1 = t * 128 + j;
    base += c;
  }
  __syncthreads();
  if (t == 0) {
    double a = (double)__half2float(__ushort_as_half((unsigned short)vk));
    double b = (double)__half2float(__ushort_as_half((unsigned short)vk1));
    double qv = (frac >= 0.5) ? (b - (b - a) * (1.0 - frac)) : (a + (b - a) * frac);
    float amax = fmaxf((float)qv, 1e-5f);
    scl[0] = amax;
    scl[1] = 127.0f / amax;
  }
}

// ---------------------------------------------------------------------------
// Activation int8 quantization (fp16 source, 8 at a time)
// ---------------------------------------------------------------------------
__device__ __forceinline__ void unpack8(uint4 u, float* f) {
  __half2 h;
  h = *(__half2*)&u.x; f[0] = __low2float(h); f[1] = __high2float(h);
  h = *(__half2*)&u.y; f[2] = __low2float(h); f[3] = __high2float(h);
  h = *(__half2*)&u.z; f[4] = __low2float(h); f[5] = __high2float(h);
  h = *(__half2*)&u.w; f[6] = __low2float(h); f[7] = __high2float(h);
}

__device__ __forceinline__ unsigned qpack4(float a, float b, float c, float d, float s) {
  int qa = (int)fminf(127.f, fmaxf(-128.f, rintf(a * s)));
  int qb = (int)fminf(127.f, fmaxf(-128.f, rintf(b * s)));
  int qc = (int)fminf(127.f, fmaxf(-128.f, rintf(c * s)));
  int qd = (int)fminf(127.f, fmaxf(-128.f, rintf(d * s)));
  return (unsigned)(qa & 255) | ((unsigned)(qb & 255) << 8) |
         ((unsigned)(qc & 255) << 16) | ((unsigned)(qd & 255) << 24);
}

__global__ __launch_bounds__(256) void k_quant16(const uint4* __restrict__ p,
                                                 uint2* __restrict__ q, size_t n8,
                                                 const float* __restrict__ scl) {
  float s = scl[1];
  size_t stride = (size_t)gridDim.x * blockDim.x;
  for (size_t i = (size_t)blockIdx.x * blockDim.x + threadIdx.x; i < n8; i += stride) {
    float f[8];
    unpack8(p[i], f);
    uint2 r;
    r.x = qpack4(f[0], f[1], f[2], f[3], s);
    r.y = qpack4(f[4], f[5], f[6], f[7], s);
    q[i] = r;
  }
}

// ---------------------------------------------------------------------------
// GELU via Abramowitz-Stegun 7.1.26 erf (abs err 1.5e-7), ~13 VALU ops
// ---------------------------------------------------------------------------
__device__ __forceinline__ float gelu_fast(float v) {
  float a = fabsf(v) * 0.70710678118654752f;
  float t = __builtin_amdgcn_rcpf(fmaf(0.3275911f, a, 1.0f));
  float p = t * fmaf(t, fmaf(t, fmaf(t, fmaf(t, 1.061405429f, -1.453152027f),
                                     1.421413741f), -0.284496736f), 0.254829592f);
  float e = __expf(-a * a);
  float er = fmaf(-p, e, 1.0f);       // erf(|u|)
  float erf_s = copysignf(er, v);
  return 0.5f * v * (1.0f + erf_s);
}

// ---------------------------------------------------------------------------
// int8 GEMM, C = A[M,K] * B[N,K]^T.  128x128 tile, BK=128 (32 KB LDS),
// global_load_lds width-16 staging, XOR granule swizzle (8 granules/row:
// slot = c ^ (row&7) -> 2-way bank aliasing = free).  4 waves, each 4x4 of
// 16x16x64 i8 MFMAs.  Epilogue: dequant (+fast GELU -> fp16 | fp32).
// ---------------------------------------------------------------------------
template <bool GELU>
__global__ __launch_bounds__(256) void k_gemm(const signed char* __restrict__ A,
                                              const signed char* __restrict__ B,
                                              int K, int N, void* __restrict__ outp,
                                              const float* __restrict__ gamma_p,
                                              const float* __restrict__ scl) {
  __shared__ __align__(16) signed char As[16384];
  __shared__ __align__(16) signed char Bs[16384];
  const int t = threadIdx.x;
  const int l = t & 63;
  const int wv = t >> 6;
  const int wr = (wv >> 1) * 64, wc = (wv & 1) * 64;
  const int m0 = blockIdx.y * 128, n0 = blockIdx.x * 128;

  // staging: slot g = c*256+t holds global granule (row g>>3, col (g&7)^(row&7))
  const signed char* ag[4]; const signed char* bg[4];
  signed char* al[4]; signed char* bl[4];
#pragma unroll
  for (int c = 0; c < 4; ++c) {
    int g = c * 256 + t;
    int r = g >> 3;
    int cg = (g & 7) ^ (r & 7);
    ag[c] = A + (size_t)(m0 + r) * K + cg * 16;
    bg[c] = B + (size_t)(n0 + r) * K + cg * 16;
    al[c] = As + g * 16;
    bl[c] = Bs + g * 16;
  }

  // fragment LDS byte offsets: row m, k-granule c = s*4 + (l>>4), slot c^(m&7)
  int a_off[2][4], b_off[2][4];
#pragma unroll
  for (int s = 0; s < 2; ++s)
#pragma unroll
    for (int i = 0; i < 4; ++i) {
      int c = s * 4 + (l >> 4);
      int am = wr + i * 16 + (l & 15);
      a_off[s][i] = (am * 8 + (c ^ (am & 7))) * 16;
      int bn = wc + i * 16 + (l & 15);
      b_off[s][i] = (bn * 8 + (c ^ (bn & 7))) * 16;
    }

  i32x4 acc[4][4];
#pragma unroll
  for (int mi = 0; mi < 4; ++mi)
#pragma unroll
    for (int ni = 0; ni < 4; ++ni) {
      i32x4 z = {0, 0, 0, 0};
      acc[mi][ni] = z;
    }

  for (int kk = 0; kk < K; kk += 128) {
    __syncthreads();
#pragma unroll
    for (int c = 0; c < 4; ++c) {
      load_lds16(ag[c] + kk, al[c]);
      load_lds16(bg[c] + kk, bl[c]);
    }
    __syncthreads();
#pragma unroll
    for (int s = 0; s < 2; ++s) {
      i32x4 af[4], bf[4];
#pragma unroll
      for (int i = 0; i < 4; ++i) af[i] = *(const i32x4*)(As + a_off[s][i]);
#pragma unroll
      for (int i = 0; i < 4; ++i) bf[i] = *(const i32x4*)(Bs + b_off[s][i]);
#pragma unroll
      for (int mi = 0; mi < 4; ++mi)
#pragma unroll
        for (int ni = 0; ni < 4; ++ni)
          acc[mi][ni] = __builtin_amdgcn_mfma_i32_16x16x64_i8(af[mi], bf[ni], acc[mi][ni], 0, 0, 0);
    }
  }

  // dequant: xq = n/s, wq = m*gamma -> contribution (gamma/s) * (n·m)
  const float cs = (*gamma_p) / scl[1];
  const int col0 = n0 + wc + (l & 15);
  const int row00 = m0 + wr + (l >> 4) * 4;
#pragma unroll
  for (int mi = 0; mi < 4; ++mi) {
#pragma unroll
    for (int ni = 0; ni < 4; ++ni) {
      int col = col0 + ni * 16;
      int rbase = row00 + mi * 16;
#pragma unroll
      for (int r = 0; r < 4; ++r) {
        float v = cs * (float)acc[mi][ni][r];
        size_t idx = (size_t)(rbase + r) * N + col;
        if (GELU) {
          ((__half*)outp)[idx] = __float2half(gelu_fast(v));
        } else {
          ((float*)outp)[idx] = v;
        }
      }
    }
  }
}

// ---------------------------------------------------------------------------
// Launcher.  Workspace layout (MB):
//   [0,128):   h2 fp16 (67.1M halfs)
//   [128,160): h1 fp16 (16.8M halfs)     -- dead after GEMM1
//   [160,176): xq1 int8                  -- dead after GEMM1
//   [128,192): xq2 int8 (reuses h1+xq1 region)
//   [192,196): w1q   [196,200): w2q
//   [200,+):   hista 128K, histb 128K, wsum[2] dbl, gamma[2] f32, scl[2][2] f32
// Peak usage ~200.3 MB (proven <= available in R1: 232 MB used).
// ---------------------------------------------------------------------------
extern "C" void kernel_launch(void* const* d_in, const int* in_sizes, int n_in,
                              void* d_out, int out_size, void* d_ws, size_t ws_size,
                              hipStream_t stream) {
  const float* x = (const float*)d_in[0];
  const float* ln_g = (const float*)d_in[1];
  const float* ln_b = (const float*)d_in[2];
  const float* w1 = (const float*)d_in[3];
  const float* w2 = (const float*)d_in[4];
  float* out = (float*)d_out;

  char* ws = (char*)d_ws;
  __half* h2 = (__half*)ws;
  __half* h1 = (__half*)(ws + ((size_t)128 << 20));
  signed char* xq1 = (signed char*)(ws + ((size_t)160 << 20));
  signed char* xq2 = (signed char*)(ws + ((size_t)128 << 20));
  signed char* w1q = (signed char*)(ws + ((size_t)192 << 20));
  signed char* w2q = (signed char*)(ws + ((size_t)196 << 20));
  char* sm = ws + ((size_t)200 << 20);
  unsigned* hista = (unsigned*)sm;
  unsigned* histb = (unsigned*)(sm + (128 << 10));
  double* wsum = (double*)(sm + (256 << 10));
  float* gamma = (float*)(sm + (256 << 10) + 16);
  float* scl1 = (float*)(sm + (256 << 10) + 32);
  float* scl2 = (float*)(sm + (256 << 10) + 40);

  // zero both histograms + scalar block (ws poisoned 0xAA before every call)
  hipMemsetAsync(sm, 0, (256 << 10) + 64, stream);

  // enable 128 KB dynamic LDS for the histogram kernel (idempotent)
  hipFuncSetAttribute((const void*)k_hist16, hipFuncAttributeMaxDynamicSharedMemorySize,
                      131072);

  // quantile ranks (np: virtual index = (1-0.005)*(N-1) in fp64)
  const double qq = 1.0 - 0.005;
  const unsigned long long N1 = (unsigned long long)M_ROWS * D_DIM;   // 16777216
  const unsigned long long N2 = (unsigned long long)M_ROWS * H_DIM;   // 67108864
  double idx1 = qq * (double)(N1 - 1);
  double idx2 = qq * (double)(N2 - 1);
  unsigned long long k1 = (unsigned long long)idx1;
  unsigned long long k2 = (unsigned long long)idx2;
  double frac1 = idx1 - (double)k1;
  double frac2 = idx2 - (double)k2;

  const size_t nW4 = (size_t)H_DIM * D_DIM / 4;
  const double inv_nW = 1.0 / (double)(H_DIM * D_DIM);

  // ---- weights ----
  k_absmean<<<512, 256, 0, stream>>>((const float4*)w1, nW4, wsum + 0);
  k_absmean<<<512, 256, 0, stream>>>((const float4*)w2, nW4, wsum + 1);
  k_wquant<<<1024, 256, 0, stream>>>((const float4*)w1, (unsigned*)w1q, nW4, wsum + 0, inv_nW, gamma + 0);
  k_wquant<<<1024, 256, 0, stream>>>((const float4*)w2, (unsigned*)w2q, nW4, wsum + 1, inv_nW, gamma + 1);

  // ---- layernorm -> h1 fp16 ----
  k_layernorm<<<M_ROWS, 256, 0, stream>>>(x, ln_g, ln_b, h1);

  // ---- quantile 1 + quantize ----
  const size_t n8_1 = N1 / 8;
  k_hist16<<<256, 512, 131072, stream>>>((const uint4*)h1, n8_1, hista);
  k_scanq<<<1, 256, 0, stream>>>(hista, scl1, k1, frac1);
  k_quant16<<<1024, 256, 0, stream>>>((const uint4*)h1, (uint2*)xq1, n8_1, scl1);

  // ---- GEMM1: [16384,1024] x [4096,1024]^T -> gelu -> h2 fp16 ----
  k_gemm<true><<<dim3(H_DIM / 128, M_ROWS / 128), 256, 0, stream>>>(
      xq1, w1q, D_DIM, H_DIM, (void*)h2, gamma + 0, scl1);

  // ---- quantile 2 + quantize ----
  const size_t n8_2 = N2 / 8;
  k_hist16<<<256, 512, 131072, stream>>>((const uint4*)h2, n8_2, histb);
  k_scanq<<<1, 256, 0, stream>>>(histb, scl2, k2, frac2);
  k_quant16<<<2048, 256, 0, stream>>>((const uint4*)h2, (uint2*)xq2, n8_2, scl2);

  // ---- GEMM2: [16384,4096] x [1024,4096]^T -> out fp32 ----
  k_gemm<false><<<dim3(D_DIM / 128, M_ROWS / 128), 256, 0, stream>>>(
      xq2, w2q, H_DIM, D_DIM, (void*)out, gamma + 1, scl2);
}

// Round 3
// 479.814 us; speedup vs baseline: 1.3496x; 1.0583x over previous
//
#include <hip/hip_runtime.h>
#include <hip/hip_fp16.h>
#include <math.h>

// ---------------------------------------------------------------------------
// FeedForward: LN -> act-int8-fakequant x ternary-weight qlinear -> GELU(erf)
//              -> qlinear.  Exact-integer i8 MFMA GEMMs (32x32x32).
// h1/h2 fp16 -> exact per-tensor quantile via 32768-bin |bits| histogram.
// Shapes: x[16384,1024], w1[4096,1024], w2[1024,4096], out[16384,1024] fp32.
// ---------------------------------------------------------------------------

#define M_ROWS 16384
#define D_DIM  1024
#define H_DIM  4096

typedef int i32x4 __attribute__((ext_vector_type(4)));
typedef int i32x16 __attribute__((ext_vector_type(16)));

#define AS1 __attribute__((address_space(1)))
#define AS3 __attribute__((address_space(3)))

__device__ __forceinline__ void load_lds16(const void* g, void* l) {
  __builtin_amdgcn_global_load_lds((const AS1 void*)g, (AS3 void*)l, 16, 0, 0);
}

// ---------------------------------------------------------------------------
// LayerNorm: one block (256 thr) per row of 1024; fp16 output.
// ---------------------------------------------------------------------------
__device__ __forceinline__ float block_sum256(float v, float* lds) {
#pragma unroll
  for (int o = 32; o > 0; o >>= 1) v += __shfl_down(v, o, 64);
  int t = threadIdx.x;
  __syncthreads();
  if ((t & 63) == 0) lds[t >> 6] = v;
  __syncthreads();
  return lds[0] + lds[1] + lds[2] + lds[3];
}

__global__ __launch_bounds__(256) void k_layernorm(
    const float* __restrict__ x, const float* __restrict__ g,
    const float* __restrict__ b, __half* __restrict__ out) {
  __shared__ float lds[4];
  int row = blockIdx.x, t = threadIdx.x;
  float4 v = ((const float4*)(x + (size_t)row * D_DIM))[t];
  float s = v.x + v.y + v.z + v.w;
  s = block_sum256(s, lds);
  float mu = s * (1.0f / D_DIM);
  float d0 = v.x - mu, d1 = v.y - mu, d2 = v.z - mu, d3 = v.w - mu;
  float ss = d0 * d0 + d1 * d1 + d2 * d2 + d3 * d3;
  ss = block_sum256(ss, lds);
  float inv = 1.0f / sqrtf(ss * (1.0f / D_DIM) + 1e-5f);
  float4 gg = ((const float4*)g)[t];
  float4 bb = ((const float4*)b)[t];
  __half2 p0 = __floats2half2_rn(d0 * inv * gg.x + bb.x, d1 * inv * gg.y + bb.y);
  __half2 p1 = __floats2half2_rn(d2 * inv * gg.z + bb.z, d3 * inv * gg.w + bb.w);
  uint2 st;
  st.x = *(unsigned*)&p0;
  st.y = *(unsigned*)&p1;
  ((uint2*)(out + (size_t)row * D_DIM))[t] = st;
}

// ---------------------------------------------------------------------------
// Weight ternary quantization (both weights in one launch each phase)
// ---------------------------------------------------------------------------
__global__ __launch_bounds__(256) void k_absmean2(const float4* __restrict__ w1,
                                                  const float4* __restrict__ w2,
                                                  size_t n4, double* __restrict__ out) {
  int which = (blockIdx.x >= (gridDim.x >> 1)) ? 1 : 0;
  const float4* p = which ? w2 : w1;
  unsigned half_grid = gridDim.x >> 1;
  unsigned blk = blockIdx.x - which * half_grid;
  double s = 0.0;
  size_t stride = (size_t)half_grid * blockDim.x;
  for (size_t i = (size_t)blk * blockDim.x + threadIdx.x; i < n4; i += stride) {
    float4 v = p[i];
    s += (double)fabsf(v.x) + (double)fabsf(v.y) + (double)fabsf(v.z) + (double)fabsf(v.w);
  }
#pragma unroll
  for (int o = 32; o > 0; o >>= 1) s += __shfl_down(s, o, 64);
  __shared__ double ds[4];
  int t = threadIdx.x;
  if ((t & 63) == 0) ds[t >> 6] = s;
  __syncthreads();
  if (t == 0) atomicAdd(out + which, ds[0] + ds[1] + ds[2] + ds[3]);
}

__device__ __forceinline__ int tern1(float w, float gamma) {
  return (int)fminf(1.f, fmaxf(-1.f, rintf(w / gamma)));
}

__global__ __launch_bounds__(256) void k_wquant2(const float4* __restrict__ w1,
                                                 const float4* __restrict__ w2,
                                                 unsigned* __restrict__ q1,
                                                 unsigned* __restrict__ q2, size_t n4,
                                                 const double* __restrict__ sump,
                                                 double inv_n, float* __restrict__ gamma_out) {
  int which = (blockIdx.x >= (gridDim.x >> 1)) ? 1 : 0;
  const float4* w = which ? w2 : w1;
  unsigned* wq = which ? q2 : q1;
  unsigned half_grid = gridDim.x >> 1;
  unsigned blk = blockIdx.x - which * half_grid;
  float gamma = (float)(sump[which] * inv_n) + 1e-5f;
  if (blk == 0 && threadIdx.x == 0) gamma_out[which] = gamma;
  size_t stride = (size_t)half_grid * blockDim.x;
  for (size_t i = (size_t)blk * blockDim.x + threadIdx.x; i < n4; i += stride) {
    float4 v = w[i];
    int a = tern1(v.x, gamma), b = tern1(v.y, gamma), c = tern1(v.z, gamma), d = tern1(v.w, gamma);
    wq[i] = (unsigned)(a & 255) | ((unsigned)(b & 255) << 8) |
            ((unsigned)(c & 255) << 16) | ((unsigned)(d & 255) << 24);
  }
}

// ---------------------------------------------------------------------------
// Exact fp16 quantile: 32768-bin histogram over |bits| (monotone for halfs).
// ---------------------------------------------------------------------------
__global__ __launch_bounds__(512) void k_hist16(const uint4* __restrict__ p, size_t n8,
                                                unsigned* __restrict__ hist) {
  extern __shared__ unsigned h[];  // 32768 bins
  int t = threadIdx.x;
  for (int i = t; i < 32768; i += 512) h[i] = 0;
  __syncthreads();
  size_t stride = (size_t)gridDim.x * 512;
  for (size_t i = (size_t)blockIdx.x * 512 + t; i < n8; i += stride) {
    uint4 u = p[i];
    atomicAdd(&h[u.x & 0x7FFFu], 1u);
    atomicAdd(&h[(u.x >> 16) & 0x7FFFu], 1u);
    atomicAdd(&h[u.y & 0x7FFFu], 1u);
    atomicAdd(&h[(u.y >> 16) & 0x7FFFu], 1u);
    atomicAdd(&h[u.z & 0x7FFFu], 1u);
    atomicAdd(&h[(u.z >> 16) & 0x7FFFu], 1u);
    atomicAdd(&h[u.w & 0x7FFFu], 1u);
    atomicAdd(&h[(u.w >> 16) & 0x7FFFu], 1u);
  }
  __syncthreads();
  for (int i = t; i < 32768; i += 512) {
    unsigned c = h[i];
    if (c) atomicAdd(&hist[i], c);
  }
}

// scan 32768 bins; order stats a[k], a[k+1]; numpy lerp -> amax, scale
__global__ __launch_bounds__(256) void k_scanq(const unsigned* __restrict__ hist,
                                               float* __restrict__ scl,
                                               unsigned long long k, double frac) {
  __shared__ unsigned tsum[256];
  __shared__ unsigned long long pre[256];
  __shared__ unsigned vk, vk1;
  int t = threadIdx.x;
  unsigned s = 0;
  for (int j = 0; j < 128; ++j) s += hist[t * 128 + j];
  tsum[t] = s;
  __syncthreads();
  if (t == 0) {
    unsigned long long c = 0;
    for (int i = 0; i < 256; ++i) { pre[i] = c; c += tsum[i]; }
  }
  __syncthreads();
  unsigned long long base = pre[t];
  for (int j = 0; j < 128; ++j) {
    unsigned c = hist[t * 128 + j];
    if (base <= k && k < base + c) vk = t * 128 + j;
    if (base <= k + 1 && k + 1 < base + c) vk1 = t * 128 + j;
    base += c;
  }
  __syncthreads();
  if (t == 0) {
    double a = (double)__half2float(__ushort_as_half((unsigned short)vk));
    double b = (double)__half2float(__ushort_as_half((unsigned short)vk1));
    double qv = (frac >= 0.5) ? (b - (b - a) * (1.0 - frac)) : (a + (b - a) * frac);
    float amax = fmaxf((float)qv, 1e-5f);
    scl[0] = amax;
    scl[1] = 127.0f / amax;
  }
}

// ---------------------------------------------------------------------------
// Activation int8 quantization (fp16 source, 8 at a time)
// ---------------------------------------------------------------------------
__device__ __forceinline__ void unpack8(uint4 u, float* f) {
  __half2 h;
  h = *(__half2*)&u.x; f[0] = __low2float(h); f[1] = __high2float(h);
  h = *(__half2*)&u.y; f[2] = __low2float(h); f[3] = __high2float(h);
  h = *(__half2*)&u.z; f[4] = __low2float(h); f[5] = __high2float(h);
  h = *(__half2*)&u.w; f[6] = __low2float(h); f[7] = __high2float(h);
}

__device__ __forceinline__ unsigned qpack4(float a, float b, float c, float d, float s) {
  int qa = (int)fminf(127.f, fmaxf(-128.f, rintf(a * s)));
  int qb = (int)fminf(127.f, fmaxf(-128.f, rintf(b * s)));
  int qc = (int)fminf(127.f, fmaxf(-128.f, rintf(c * s)));
  int qd = (int)fminf(127.f, fmaxf(-128.f, rintf(d * s)));
  return (unsigned)(qa & 255) | ((unsigned)(qb & 255) << 8) |
         ((unsigned)(qc & 255) << 16) | ((unsigned)(qd & 255) << 24);
}

__global__ __launch_bounds__(256) void k_quant16(const uint4* __restrict__ p,
                                                 uint2* __restrict__ q, size_t n8,
                                                 const float* __restrict__ scl) {
  float s = scl[1];
  size_t stride = (size_t)gridDim.x * blockDim.x;
  for (size_t i = (size_t)blockIdx.x * blockDim.x + threadIdx.x; i < n8; i += stride) {
    float f[8];
    unpack8(p[i], f);
    uint2 r;
    r.x = qpack4(f[0], f[1], f[2], f[3], s);
    r.y = qpack4(f[4], f[5], f[6], f[7], s);
    q[i] = r;
  }
}

// ---------------------------------------------------------------------------
// GELU via Abramowitz-Stegun 7.1.26 erf (abs err 1.5e-7)
// ---------------------------------------------------------------------------
__device__ __forceinline__ float gelu_fast(float v) {
  float a = fabsf(v) * 0.70710678118654752f;
  float t = __builtin_amdgcn_rcpf(fmaf(0.3275911f, a, 1.0f));
  float p = t * fmaf(t, fmaf(t, fmaf(t, fmaf(t, 1.061405429f, -1.453152027f),
                                     1.421413741f), -0.284496736f), 0.254829592f);
  float e = __expf(-a * a);
  float er = fmaf(-p, e, 1.0f);
  float erf_s = copysignf(er, v);
  return 0.5f * v * (1.0f + erf_s);
}

// ---------------------------------------------------------------------------
// int8 GEMM, C = A[M,K] * B[N,K]^T.  128x128 tile, BK=128 (32 KB LDS),
// compile-time K (full unroll, immediate global_load_lds offsets within
// 512-byte macro-iterations), XOR granule swizzle slot = g ^ (row&7)
// (bank-optimal: 8 lanes per 4-bank cluster = LDS minimum for b128).
// 4 waves, each 2x2 of 32x32x32 i8 MFMAs.  __launch_bounds__(256,4) caps
// unified VGPR at 128 -> 4 blocks/CU (R2 was ~2.4, reg-file-limited).
// ---------------------------------------------------------------------------
template <int K, bool GELU>
__global__ __launch_bounds__(256, 4) void k_gemm(const signed char* __restrict__ A,
                                                 const signed char* __restrict__ B,
                                                 int N, void* __restrict__ outp,
                                                 const float* __restrict__ gamma_p,
                                                 const float* __restrict__ scl) {
  __shared__ __align__(16) signed char As[16384];
  __shared__ __align__(16) signed char Bs[16384];
  const int t = threadIdx.x;
  const int l = t & 63;
  const int wv = t >> 6;
  const int wr = (wv >> 1) * 64, wc = (wv & 1) * 64;
  const int m0 = blockIdx.y * 128, n0 = blockIdx.x * 128;

  // staging: LDS slot g = c*256+t holds global granule (row g>>3, col (g&7)^(row&7))
  const signed char* ag[4]; const signed char* bg[4];
  signed char* al[4]; signed char* bl[4];
#pragma unroll
  for (int c = 0; c < 4; ++c) {
    int g = c * 256 + t;
    int r = g >> 3;
    int cg = (g & 7) ^ (r & 7);
    ag[c] = A + (size_t)(m0 + r) * K + cg * 16;
    bg[c] = B + (size_t)(n0 + r) * K + cg * 16;
    al[c] = As + g * 16;
    bl[c] = Bs + g * 16;
  }

  // fragment offsets: A row = wr+mi*32+(l&31), k-granule g = 2*ks+(l>>5),
  // LDS slot = g ^ (row&7); byte offset = row*128 + slot*16
  int a_off[2][4], b_off[2][4];
#pragma unroll
  for (int mi = 0; mi < 2; ++mi)
#pragma unroll
    for (int ks = 0; ks < 4; ++ks) {
      int am = wr + mi * 32 + (l & 31);
      int g = 2 * ks + (l >> 5);
      a_off[mi][ks] = am * 128 + (g ^ (am & 7)) * 16;
      int bn = wc + mi * 32 + (l & 31);
      b_off[mi][ks] = bn * 128 + (g ^ (bn & 7)) * 16;
    }

  i32x16 acc[2][2];
#pragma unroll
  for (int mi = 0; mi < 2; ++mi)
#pragma unroll
    for (int ni = 0; ni < 2; ++ni)
      acc[mi][ni] = (i32x16)(0);

  for (int kk = 0; kk < K; kk += 512) {
#pragma unroll
    for (int j = 0; j < 4; ++j) {
      const int ko = j * 128;
      __syncthreads();
#pragma unroll
      for (int c = 0; c < 4; ++c) {
        load_lds16(ag[c] + kk + ko, al[c]);
        load_lds16(bg[c] + kk + ko, bl[c]);
      }
      __syncthreads();
#pragma unroll
      for (int ks = 0; ks < 4; ++ks) {
        i32x4 af[2], bf[2];
#pragma unroll
        for (int i = 0; i < 2; ++i) af[i] = *(const i32x4*)(As + a_off[i][ks]);
#pragma unroll
        for (int i = 0; i < 2; ++i) bf[i] = *(const i32x4*)(Bs + b_off[i][ks]);
#pragma unroll
        for (int mi = 0; mi < 2; ++mi)
#pragma unroll
          for (int ni = 0; ni < 2; ++ni)
            acc[mi][ni] = __builtin_amdgcn_mfma_i32_32x32x32_i8(af[mi], bf[ni], acc[mi][ni], 0, 0, 0);
      }
    }
  }

  // C/D layout (32x32): col = lane&31, row = (reg&3) + 8*(reg>>2) + 4*(lane>>5)
  const float cs = (*gamma_p) / scl[1];
  const int col0 = n0 + wc + (l & 31);
  const int row0 = m0 + wr + 4 * (l >> 5);
#pragma unroll
  for (int mi = 0; mi < 2; ++mi) {
#pragma unroll
    for (int ni = 0; ni < 2; ++ni) {
      int col = col0 + ni * 32;
#pragma unroll
      for (int reg = 0; reg < 16; ++reg) {
        int row = row0 + mi * 32 + (reg & 3) + 8 * (reg >> 2);
        float v = cs * (float)acc[mi][ni][reg];
        size_t idx = (size_t)row * N + col;
        if (GELU) {
          ((__half*)outp)[idx] = __float2half(gelu_fast(v));
        } else {
          ((float*)outp)[idx] = v;
        }
      }
    }
  }
}

// ---------------------------------------------------------------------------
// Launcher.  Workspace layout (MB):
//   [0,128):   h2 fp16          [128,160): h1 fp16 (dead after GEMM1)
//   [160,176): xq1              [128,192): xq2 (reuses h1+xq1 after GEMM1)
//   [192,196): w1q  [196,200): w2q
//   [200,+):   hista 128K, histb 128K, wsum[2] dbl, gamma[2] f32, scl pairs
// ---------------------------------------------------------------------------
extern "C" void kernel_launch(void* const* d_in, const int* in_sizes, int n_in,
                              void* d_out, int out_size, void* d_ws, size_t ws_size,
                              hipStream_t stream) {
  const float* x = (const float*)d_in[0];
  const float* ln_g = (const float*)d_in[1];
  const float* ln_b = (const float*)d_in[2];
  const float* w1 = (const float*)d_in[3];
  const float* w2 = (const float*)d_in[4];
  float* out = (float*)d_out;

  char* ws = (char*)d_ws;
  __half* h2 = (__half*)ws;
  __half* h1 = (__half*)(ws + ((size_t)128 << 20));
  signed char* xq1 = (signed char*)(ws + ((size_t)160 << 20));
  signed char* xq2 = (signed char*)(ws + ((size_t)128 << 20));
  signed char* w1q = (signed char*)(ws + ((size_t)192 << 20));
  signed char* w2q = (signed char*)(ws + ((size_t)196 << 20));
  char* sm = ws + ((size_t)200 << 20);
  unsigned* hista = (unsigned*)sm;
  unsigned* histb = (unsigned*)(sm + (128 << 10));
  double* wsum = (double*)(sm + (256 << 10));
  float* gamma = (float*)(sm + (256 << 10) + 16);
  float* scl1 = (float*)(sm + (256 << 10) + 32);
  float* scl2 = (float*)(sm + (256 << 10) + 40);

  hipMemsetAsync(sm, 0, (256 << 10) + 64, stream);
  hipFuncSetAttribute((const void*)k_hist16, hipFuncAttributeMaxDynamicSharedMemorySize,
                      131072);

  const double qq = 1.0 - 0.005;
  const unsigned long long N1 = (unsigned long long)M_ROWS * D_DIM;
  const unsigned long long N2 = (unsigned long long)M_ROWS * H_DIM;
  double idx1 = qq * (double)(N1 - 1);
  double idx2 = qq * (double)(N2 - 1);
  unsigned long long k1 = (unsigned long long)idx1;
  unsigned long long k2 = (unsigned long long)idx2;
  double frac1 = idx1 - (double)k1;
  double frac2 = idx2 - (double)k2;

  const size_t nW4 = (size_t)H_DIM * D_DIM / 4;
  const double inv_nW = 1.0 / (double)(H_DIM * D_DIM);

  // ---- weights (fused launches) ----
  k_absmean2<<<1024, 256, 0, stream>>>((const float4*)w1, (const float4*)w2, nW4, wsum);
  k_wquant2<<<2048, 256, 0, stream>>>((const float4*)w1, (const float4*)w2,
                                      (unsigned*)w1q, (unsigned*)w2q, nW4, wsum, inv_nW, gamma);

  // ---- layernorm -> h1 fp16 ----
  k_layernorm<<<M_ROWS, 256, 0, stream>>>(x, ln_g, ln_b, h1);

  // ---- quantile 1 + quantize ----
  const size_t n8_1 = N1 / 8;
  k_hist16<<<256, 512, 131072, stream>>>((const uint4*)h1, n8_1, hista);
  k_scanq<<<1, 256, 0, stream>>>(hista, scl1, k1, frac1);
  k_quant16<<<1024, 256, 0, stream>>>((const uint4*)h1, (uint2*)xq1, n8_1, scl1);

  // ---- GEMM1: [16384,1024] x [4096,1024]^T -> gelu -> h2 fp16 ----
  k_gemm<D_DIM, true><<<dim3(H_DIM / 128, M_ROWS / 128), 256, 0, stream>>>(
      xq1, w1q, H_DIM, (void*)h2, gamma + 0, scl1);

  // ---- quantile 2 + quantize ----
  const size_t n8_2 = N2 / 8;
  k_hist16<<<256, 512, 131072, stream>>>((const uint4*)h2, n8_2, histb);
  k_scanq<<<1, 256, 0, stream>>>(histb, scl2, k2, frac2);
  k_quant16<<<2048, 256, 0, stream>>>((const uint4*)h2, (uint2*)xq2, n8_2, scl2);

  // ---- GEMM2: [16384,4096] x [1024,4096]^T -> out fp32 ----
  k_gemm<H_DIM, false><<<dim3(D_DIM / 128, M_ROWS / 128), 256, 0, stream>>>(
      xq2, w2q, D_DIM, (void*)out, gamma + 1, scl2);
}